// Round 10
// baseline (424.882 us; speedup 1.0000x reference)
//
#include <hip/hip_runtime.h>
#include <hip/hip_fp16.h>
#include <math.h>

#define D 128
#define NBUCK_MAX 128
#define BROWS 1024   // rows per bucket (bshift=10); requires N <= 131072 (col packs in 17 bits)

typedef _Float16 f16x8 __attribute__((ext_vector_type(8)));
typedef _Float16 f16x2 __attribute__((ext_vector_type(2)));
typedef __attribute__((ext_vector_type(4))) float f32x4;

static __device__ __forceinline__ unsigned short f2h(float f) {
  __half h = __float2half(f);
  return *reinterpret_cast<unsigned short*>(&h);
}
static __device__ __forceinline__ float hlo(unsigned u) {
  __half2 h = *reinterpret_cast<__half2*>(&u);
  return __low2float(h);
}
static __device__ __forceinline__ float hhi(unsigned u) {
  __half2 h = *reinterpret_cast<__half2*>(&u);
  return __high2float(h);
}
static __device__ __forceinline__ __half2 u2h(unsigned u) { return *reinterpret_cast<__half2*>(&u); }
static __device__ __forceinline__ unsigned h2u(__half2 h) { return *reinterpret_cast<unsigned*>(&h); }
static __device__ __forceinline__ unsigned relu2(unsigned u) {
  f16x2 v = *reinterpret_cast<f16x2*>(&u);
  v = __builtin_elementwise_max(v, (f16x2)(_Float16)0.0f);
  return *reinterpret_cast<unsigned*>(&v);
}

// ---- radix partition by bucket (row >> bshift), WG-private histograms ----
__global__ __launch_bounds__(256) void wg_hist(const int* __restrict__ rows, int* __restrict__ wghist,
                                               int E, int NW, int per, int bshift) {
  __shared__ int cnt[NBUCK_MAX];
  int tid = threadIdx.x, w = blockIdx.x;
  if (tid < NBUCK_MAX) cnt[tid] = 0;
  __syncthreads();
  int base = w * per;
  int end = base + per; if (end > E) end = E;
  for (int e = base + tid; e < end; e += 256) atomicAdd(&cnt[rows[e] >> bshift], 1);
  __syncthreads();
  if (tid < NBUCK_MAX) wghist[tid * NW + w] = cnt[tid];
}

__global__ __launch_bounds__(512) void scan_wg(const int* __restrict__ wghist, int* __restrict__ wgstart,
                                               int* __restrict__ btot, int NW) {
  int b = blockIdx.x, t = threadIdx.x;
  __shared__ int s[512];
  int v = (t < NW) ? wghist[b * NW + t] : 0;
  s[t] = v;
  __syncthreads();
  for (int d = 1; d < 512; d <<= 1) {
    int x = (t >= d) ? s[t - d] : 0;
    __syncthreads();
    s[t] += x;
    __syncthreads();
  }
  if (t < NW) wgstart[b * NW + t] = s[t] - v;
  if (t == 511) btot[b] = s[511];
}

__global__ __launch_bounds__(128) void scan_buckets(const int* __restrict__ btot, int* __restrict__ bstart, int NBUCK) {
  int t = threadIdx.x;
  __shared__ int s[128];
  int v = (t < NBUCK) ? btot[t] : 0;
  s[t] = v;
  __syncthreads();
  for (int d = 1; d < 128; d <<= 1) {
    int x = (t >= d) ? s[t - d] : 0;
    __syncthreads();
    s[t] += x;
    __syncthreads();
  }
  if (t < NBUCK) bstart[t] = s[t] - v;
  if (t == 127) bstart[NBUCK] = s[127];
}

__global__ __launch_bounds__(256) void partition_kernel(const int* __restrict__ rows, const int* __restrict__ cols,
                                                        const float* __restrict__ vals, const int* __restrict__ wgstart,
                                                        const int* __restrict__ bstart,
                                                        uint2* __restrict__ gbin, int E, int NW, int per, int bshift) {
  __shared__ int cur[NBUCK_MAX];
  int tid = threadIdx.x, w = blockIdx.x;
  if (tid < NBUCK_MAX) cur[tid] = bstart[tid] + wgstart[tid * NW + w];
  __syncthreads();
  unsigned rmask = (1u << bshift) - 1u;
  int base = w * per;
  int end = base + per; if (end > E) end = E;
  for (int e = base + tid; e < end; e += 256) {
    unsigned r = (unsigned)rows[e];
    int b = r >> bshift;
    int pos = atomicAdd(&cur[b], 1);
    gbin[pos] = make_uint2(((r & rmask) << 17) | (unsigned)cols[e], __float_as_uint(vals[e]));
  }
}

// per-bucket: LDS row-histogram + scan -> row offsets; scatter into final CSR ep
// ep entry: .x = Y-row byte offset (col*256), .y = val as packed half2 (h | h<<16)
// last bucket also zero-pads ep[E..E+31] so spmm can load unguarded.
__global__ __launch_bounds__(256) void debin2(const uint2* __restrict__ gbin, const int* __restrict__ bstart,
                                              int* __restrict__ offsets, uint2* __restrict__ ep,
                                              int N, int E, int bshift, int NBUCK) {
  __shared__ int cnt[BROWS];
  __shared__ int sblk[256];
  int b = blockIdx.x, t = threadIdx.x;
  int r0 = b << bshift;
  int r1 = r0 + BROWS; if (r1 > N) r1 = N;
  int nr = r1 - r0;
  int s0 = bstart[b], e0 = bstart[b + 1];
#pragma unroll
  for (int q = 0; q < 4; ++q) cnt[t * 4 + q] = 0;
  __syncthreads();
  for (int i = s0 + t; i < e0; i += 256) atomicAdd(&cnt[gbin[i].x >> 17], 1);
  __syncthreads();
  int c[4]; int tsum = 0;
#pragma unroll
  for (int q = 0; q < 4; ++q) { c[q] = cnt[4 * t + q]; tsum += c[q]; }
  sblk[t] = tsum;
  __syncthreads();
  for (int d = 1; d < 256; d <<= 1) {
    int x = (t >= d) ? sblk[t - d] : 0;
    __syncthreads();
    sblk[t] += x;
    __syncthreads();
  }
  int run = s0 + sblk[t] - tsum;
#pragma unroll
  for (int q = 0; q < 4; ++q) {
    int j = 4 * t + q;
    if (j < nr) offsets[r0 + j] = run;
    cnt[j] = run;   // reuse as absolute cursor
    run += c[q];
  }
  __syncthreads();
  for (int i = s0 + t; i < e0; i += 256) {
    uint2 en = gbin[i];
    int lr = (int)(en.x >> 17);
    int pos = atomicAdd(&cnt[lr], 1);
    unsigned short h = f2h(__uint_as_float(en.y));
    ep[pos] = make_uint2((en.x & 0x1FFFFu) << 8, ((unsigned)h << 16) | (unsigned)h);
  }
  if (b == NBUCK - 1) {
    if (t == 0) offsets[N] = E;
    if (t < 32) ep[E + t] = make_uint2(0u, 0u);   // zero-val pad for unguarded gather
  }
}

// ---------------- fp32 -> fp16 converter (emb and W in one launch) ----------------
__global__ __launch_bounds__(256) void conv_f16(const float* __restrict__ a, unsigned short* __restrict__ oa,
                                                const float* __restrict__ bsrc, unsigned short* __restrict__ ob,
                                                int n8a, int n8tot) {
  int t = blockIdx.x * 256 + threadIdx.x;
  if (t >= n8tot) return;
  const float* src = (t < n8a) ? a : bsrc;
  unsigned short* dst = (t < n8a) ? oa : ob;
  int idx = (t < n8a) ? t : t - n8a;
  size_t base = (size_t)idx * 8;
  float4 x = *(const float4*)&src[base];
  float4 y = *(const float4*)&src[base + 4];
  ushort4 o0, o1;
  o0.x = f2h(x.x); o0.y = f2h(x.y); o0.z = f2h(x.z); o0.w = f2h(x.w);
  o1.x = f2h(y.x); o1.y = f2h(y.y); o1.z = f2h(y.z); o1.w = f2h(y.w);
  *(ushort4*)&dst[base] = o0;
  *(ushort4*)&dst[base + 4] = o1;
}

// ---------------- GEMM (MFMA f16): Y[r][c] = sum_k X[r][k] * Wl[c][k] ----------------
__global__ __launch_bounds__(256) void gemm_mfma(const unsigned short* __restrict__ xb,
                                                 const unsigned short* __restrict__ wb,
                                                 unsigned short* __restrict__ Y, int N) {
  int wave = threadIdx.x >> 6, lane = threadIdx.x & 63;
  int r0 = blockIdx.x * 64 + wave * 16;
  if (r0 >= N) return;
  int lr = lane & 15, lk = lane >> 4;
  const unsigned short* xrow = xb + (size_t)(r0 + lr) * D + lk * 8;
  f16x8 xf[4];
#pragma unroll
  for (int s = 0; s < 4; ++s) xf[s] = *(const f16x8*)(xrow + 32 * s);
  f32x4 acc[8];
#pragma unroll
  for (int mt = 0; mt < 8; ++mt) acc[mt] = (f32x4){0.f, 0.f, 0.f, 0.f};
#pragma unroll
  for (int mt = 0; mt < 8; ++mt) {
    const unsigned short* wrow = wb + (size_t)(mt * 16 + lr) * D + lk * 8;
#pragma unroll
    for (int s = 0; s < 4; ++s) {
      f16x8 wf = *(const f16x8*)(wrow + 32 * s);
      acc[mt] = __builtin_amdgcn_mfma_f32_16x16x32_f16(wf, xf[s], acc[mt], 0, 0, 0);
    }
  }
#pragma unroll
  for (int mt = 0; mt < 8; ++mt) {
    ushort4 o;
    o.x = f2h(acc[mt][0]); o.y = f2h(acc[mt][1]); o.z = f2h(acc[mt][2]); o.w = f2h(acc[mt][3]);
    *(ushort4*)&Y[(size_t)(r0 + lr) * D + mt * 16 + lk * 4] = o;
  }
}

// ---------------- SpMM + ReLU -> fp16 Xn + row norm (packed half2, unguarded loads) ----------------
__global__ __launch_bounds__(256) void spmm_kernel(const char* __restrict__ Yb, const int* __restrict__ offs,
                                                   const uint2* __restrict__ ep,
                                                   unsigned* __restrict__ Xn, float* __restrict__ nrm, int N) {
  int w = threadIdx.x >> 6, lane = threadIdx.x & 63;
  int r = blockIdx.x * 4 + w;
  if (r >= N) return;
  int g = lane >> 4, l = lane & 15;
  int s = offs[r], e = offs[r + 1];
  unsigned acc[4] = {0u, 0u, 0u, 0u};   // 4x packed half2
  int loff = l * 16;
  for (int base = s; base < e; base += 32) {
    uint2 ed[8];
#pragma unroll
    for (int q = 0; q < 8; ++q) ed[q] = ep[base + 4 * q + g];   // unguarded (ep padded by 32)
    uint4 yv[8];
#pragma unroll
    for (int q = 0; q < 8; ++q) yv[q] = *(const uint4*)(Yb + (size_t)(ed[q].x + loff));
#pragma unroll
    for (int q = 0; q < 8; ++q) {
      unsigned fm = (base + 4 * q + g < e) ? ed[q].y : 0u;      // mask val only
      __half2 f2 = u2h(fm);
      unsigned uu[4] = {yv[q].x, yv[q].y, yv[q].z, yv[q].w};
#pragma unroll
      for (int k = 0; k < 4; ++k) {
        __half2 a2 = __hfma2(u2h(uu[k]), f2, u2h(acc[k]));
        acc[k] = h2u(a2);
      }
    }
  }
  // cross-group reduce (f16 packed), then ReLU
#pragma unroll
  for (int k = 0; k < 4; ++k) {
    unsigned a = acc[k];
    unsigned b = (unsigned)__shfl_xor((int)a, 16);
    a = h2u(__hadd2(u2h(a), u2h(b)));
    b = (unsigned)__shfl_xor((int)a, 32);
    a = relu2(h2u(__hadd2(u2h(a), u2h(b))));
    acc[k] = a;
  }
  // row norm (fp32 squares)
  float ss = 0.f;
#pragma unroll
  for (int k = 0; k < 4; ++k) {
    float lo = hlo(acc[k]), hi = hhi(acc[k]);
    ss = fmaf(lo, lo, ss);
    ss = fmaf(hi, hi, ss);
  }
  ss += __shfl_xor(ss, 1);
  ss += __shfl_xor(ss, 2);
  ss += __shfl_xor(ss, 4);
  ss += __shfl_xor(ss, 8);
  if (lane == 0) nrm[r] = sqrtf(ss);
  if (g == 0) {
    uint4 o = make_uint4(acc[0], acc[1], acc[2], acc[3]);
    *(uint4*)&Xn[(size_t)r * (D / 2) + l * 4] = o;
  }
}

// ---------------- final combine: 4 rows/wave, 16B loads ----------------
__global__ __launch_bounds__(256) void combine_kernel(const unsigned short* __restrict__ x0,
                                                      const unsigned short* __restrict__ x1,
                                                      const unsigned short* __restrict__ x2,
                                                      const unsigned short* __restrict__ x3,
                                                      const float* __restrict__ nrm,
                                                      float* __restrict__ out, int N, float scl) {
  int wave = threadIdx.x >> 6, lane = threadIdx.x & 63;
  int sub = lane >> 4, l = lane & 15;
  int r = blockIdx.x * 16 + wave * 4 + sub;
  if (r >= N) return;
  size_t p = (size_t)r * D + l * 8;
  uint4 a0 = *(const uint4*)&x0[p];
  unsigned w0[4] = {a0.x, a0.y, a0.z, a0.w};
  float ss = 0.f;
#pragma unroll
  for (int k = 0; k < 4; ++k) {
    float lo = hlo(w0[k]), hi = hhi(w0[k]);
    ss = fmaf(lo, lo, ss);
    ss = fmaf(hi, hi, ss);
  }
  ss += __shfl_xor(ss, 1);
  ss += __shfl_xor(ss, 2);
  ss += __shfl_xor(ss, 4);
  ss += __shfl_xor(ss, 8);
  float s0 = scl / fmaxf(sqrtf(ss), 1e-12f);
  float i1 = scl / fmaxf(nrm[r], 1e-12f);
  float i2 = scl / fmaxf(nrm[N + r], 1e-12f);
  float i3 = scl / fmaxf(nrm[2 * N + r], 1e-12f);
  uint4 a1 = *(const uint4*)&x1[p];
  uint4 a2 = *(const uint4*)&x2[p];
  uint4 a3 = *(const uint4*)&x3[p];
  unsigned w1[4] = {a1.x, a1.y, a1.z, a1.w};
  unsigned w2[4] = {a2.x, a2.y, a2.z, a2.w};
  unsigned w3[4] = {a3.x, a3.y, a3.z, a3.w};
  float o[8];
#pragma unroll
  for (int k = 0; k < 4; ++k) {
    o[2 * k]     = s0 * hlo(w0[k]) + i1 * hlo(w1[k]) + i2 * hlo(w2[k]) + i3 * hlo(w3[k]);
    o[2 * k + 1] = s0 * hhi(w0[k]) + i1 * hhi(w1[k]) + i2 * hhi(w2[k]) + i3 * hhi(w3[k]);
  }
  *(float4*)&out[p]     = make_float4(o[0], o[1], o[2], o[3]);
  *(float4*)&out[p + 4] = make_float4(o[4], o[5], o[6], o[7]);
}

// ---------------- launch ----------------
extern "C" void kernel_launch(void* const* d_in, const int* in_sizes, int n_in,
                              void* d_out, int out_size, void* d_ws, size_t ws_size,
                              hipStream_t stream) {
  const int* rows = (const int*)d_in[0];
  const int* cols = (const int*)d_in[1];
  const float* vals = (const float*)d_in[2];
  const float* emb = (const float*)d_in[3];
  const float* W = (const float*)d_in[4];
  float* out = (float*)d_out;

  int E = in_sizes[0];
  int N = in_sizes[3] / D;
  int L = in_sizes[4] / (D * D);
  float scl = 1.0f / (float)(L + 1);

  int bshift = 10;
  int NBUCK = (N + (1 << bshift) - 1) >> bshift;

  int per = 4096;
  while ((E + per - 1) / per > 512) per *= 2;
  int NW = (E + per - 1) / per;

  char* ws = (char*)d_ws;
  size_t off = 0;
  auto take = [&](size_t bytes) -> void* {
    void* p = ws + off;
    off += (bytes + 255) & ~(size_t)255;
    return p;
  };
  unsigned short* xb0 = (unsigned short*)take((size_t)N * D * 2);
  unsigned short* xb1 = (unsigned short*)take((size_t)N * D * 2);
  unsigned short* xb2 = (unsigned short*)take((size_t)N * D * 2);
  unsigned short* xb3 = (unsigned short*)take((size_t)N * D * 2);
  unsigned short* yB  = (unsigned short*)take((size_t)N * D * 2);
  unsigned short* wb  = (unsigned short*)take((size_t)L * D * D * 2);
  float* nrm = (float*)take((size_t)L * N * sizeof(float));
  int* offsets = (int*)take((size_t)(N + 1) * 4);
  int* wghist = (int*)take((size_t)NBUCK_MAX * NW * 4);
  int* wgstart = (int*)take((size_t)NBUCK_MAX * NW * 4);
  int* btot = (int*)take((size_t)NBUCK_MAX * 4);
  int* bstart = (int*)take((size_t)(NBUCK_MAX + 1) * 4);
  uint2* ep = (uint2*)take((size_t)(E + 32) * 8);
  // gbin aliases xb1: consumed (debin2) strictly before spmm layer 0 writes xb1 (stream-ordered)
  uint2* gbin = (uint2*)xb1;

  // radix partition into buckets, then per-bucket offsets + scatter
  wg_hist<<<NW, 256, 0, stream>>>(rows, wghist, E, NW, per, bshift);
  scan_wg<<<NBUCK, 512, 0, stream>>>(wghist, wgstart, btot, NW);
  scan_buckets<<<1, 128, 0, stream>>>(btot, bstart, NBUCK);
  partition_kernel<<<NW, 256, 0, stream>>>(rows, cols, vals, wgstart, bstart, gbin, E, NW, per, bshift);
  debin2<<<NBUCK, 256, 0, stream>>>(gbin, bstart, offsets, ep, N, E, bshift, NBUCK);

  // fp16 conversions (emb + W in one launch)
  int n8x = N * D / 8;
  int n8w = L * D * D / 8;
  conv_f16<<<(n8x + n8w + 255) / 256, 256, 0, stream>>>(emb, xb0, W, wb, n8x, n8x + n8w);

  unsigned short* xbufs[4] = {xb0, xb1, xb2, xb3};
  int nrb = (N + 63) / 64;
  for (int l = 0; l < L; ++l) {
    gemm_mfma<<<nrb, 256, 0, stream>>>(xbufs[l], wb + (size_t)l * D * D, yB, N);
    spmm_kernel<<<(N + 3) / 4, 256, 0, stream>>>((const char*)yB, offsets, ep,
                                                 (unsigned*)xbufs[l + 1], nrm + (size_t)l * N, N);
  }
  combine_kernel<<<(N + 15) / 16, 256, 0, stream>>>(xb0, xb1, xb2, xb3, nrm, out, N, scl);
}

// Round 11
// 372.520 us; speedup vs baseline: 1.1406x; 1.1406x over previous
//
#include <hip/hip_runtime.h>
#include <hip/hip_fp16.h>
#include <math.h>

#define D 128
#define NBUCK_MAX 128
#define BROWS 1024   // rows per bucket (bshift=10); requires N <= 131072 (col packs in 17 bits)

typedef _Float16 f16x8 __attribute__((ext_vector_type(8)));
typedef _Float16 f16x2 __attribute__((ext_vector_type(2)));
typedef __attribute__((ext_vector_type(4))) float f32x4;

static __device__ __forceinline__ unsigned short f2h(float f) {
  __half h = __float2half(f);
  return *reinterpret_cast<unsigned short*>(&h);
}
static __device__ __forceinline__ float hlo(unsigned u) {
  __half2 h = *reinterpret_cast<__half2*>(&u);
  return __low2float(h);
}
static __device__ __forceinline__ float hhi(unsigned u) {
  __half2 h = *reinterpret_cast<__half2*>(&u);
  return __high2float(h);
}
static __device__ __forceinline__ __half2 u2h(unsigned u) { return *reinterpret_cast<__half2*>(&u); }
static __device__ __forceinline__ unsigned h2u(__half2 h) { return *reinterpret_cast<unsigned*>(&h); }
static __device__ __forceinline__ unsigned relu2(unsigned u) {
  f16x2 v = *reinterpret_cast<f16x2*>(&u);
  v = __builtin_elementwise_max(v, (f16x2)(_Float16)0.0f);
  return *reinterpret_cast<unsigned*>(&v);
}

// ---- radix partition by bucket (row >> bshift), WG-private histograms ----
__global__ __launch_bounds__(256) void wg_hist(const int* __restrict__ rows, int* __restrict__ wghist,
                                               int E, int NW, int per, int bshift) {
  __shared__ int cnt[NBUCK_MAX];
  int tid = threadIdx.x, w = blockIdx.x;
  if (tid < NBUCK_MAX) cnt[tid] = 0;
  __syncthreads();
  int base = w * per;
  int end = base + per; if (end > E) end = E;
  for (int e = base + tid; e < end; e += 256) atomicAdd(&cnt[rows[e] >> bshift], 1);
  __syncthreads();
  if (tid < NBUCK_MAX) wghist[tid * NW + w] = cnt[tid];
}

__global__ __launch_bounds__(512) void scan_wg(const int* __restrict__ wghist, int* __restrict__ wgstart,
                                               int* __restrict__ btot, int NW) {
  int b = blockIdx.x, t = threadIdx.x;
  __shared__ int s[512];
  int v = (t < NW) ? wghist[b * NW + t] : 0;
  s[t] = v;
  __syncthreads();
  for (int d = 1; d < 512; d <<= 1) {
    int x = (t >= d) ? s[t - d] : 0;
    __syncthreads();
    s[t] += x;
    __syncthreads();
  }
  if (t < NW) wgstart[b * NW + t] = s[t] - v;
  if (t == 511) btot[b] = s[511];
}

__global__ __launch_bounds__(128) void scan_buckets(const int* __restrict__ btot, int* __restrict__ bstart, int NBUCK) {
  int t = threadIdx.x;
  __shared__ int s[128];
  int v = (t < NBUCK) ? btot[t] : 0;
  s[t] = v;
  __syncthreads();
  for (int d = 1; d < 128; d <<= 1) {
    int x = (t >= d) ? s[t - d] : 0;
    __syncthreads();
    s[t] += x;
    __syncthreads();
  }
  if (t < NBUCK) bstart[t] = s[t] - v;
  if (t == 127) bstart[NBUCK] = s[127];
}

__global__ __launch_bounds__(256) void partition_kernel(const int* __restrict__ rows, const int* __restrict__ cols,
                                                        const float* __restrict__ vals, const int* __restrict__ wgstart,
                                                        const int* __restrict__ bstart,
                                                        uint2* __restrict__ gbin, int E, int NW, int per, int bshift) {
  __shared__ int cur[NBUCK_MAX];
  int tid = threadIdx.x, w = blockIdx.x;
  if (tid < NBUCK_MAX) cur[tid] = bstart[tid] + wgstart[tid * NW + w];
  __syncthreads();
  unsigned rmask = (1u << bshift) - 1u;
  int base = w * per;
  int end = base + per; if (end > E) end = E;
  for (int e = base + tid; e < end; e += 256) {
    unsigned r = (unsigned)rows[e];
    int b = r >> bshift;
    int pos = atomicAdd(&cur[b], 1);
    gbin[pos] = make_uint2(((r & rmask) << 17) | (unsigned)cols[e], __float_as_uint(vals[e]));
  }
}

// per-bucket: LDS row-histogram + scan -> row offsets; scatter into final CSR ep
// ep entry: .x = Y-row byte offset (col*256), .y = val as packed half2 (h | h<<16)
__global__ __launch_bounds__(256) void debin2(const uint2* __restrict__ gbin, const int* __restrict__ bstart,
                                              int* __restrict__ offsets, uint2* __restrict__ ep,
                                              int N, int E, int bshift, int NBUCK) {
  __shared__ int cnt[BROWS];
  __shared__ int sblk[256];
  int b = blockIdx.x, t = threadIdx.x;
  int r0 = b << bshift;
  int r1 = r0 + BROWS; if (r1 > N) r1 = N;
  int nr = r1 - r0;
  int s0 = bstart[b], e0 = bstart[b + 1];
#pragma unroll
  for (int q = 0; q < 4; ++q) cnt[t * 4 + q] = 0;
  __syncthreads();
  for (int i = s0 + t; i < e0; i += 256) atomicAdd(&cnt[gbin[i].x >> 17], 1);
  __syncthreads();
  int c[4]; int tsum = 0;
#pragma unroll
  for (int q = 0; q < 4; ++q) { c[q] = cnt[4 * t + q]; tsum += c[q]; }
  sblk[t] = tsum;
  __syncthreads();
  for (int d = 1; d < 256; d <<= 1) {
    int x = (t >= d) ? sblk[t - d] : 0;
    __syncthreads();
    sblk[t] += x;
    __syncthreads();
  }
  int run = s0 + sblk[t] - tsum;
#pragma unroll
  for (int q = 0; q < 4; ++q) {
    int j = 4 * t + q;
    if (j < nr) offsets[r0 + j] = run;
    cnt[j] = run;   // reuse as absolute cursor
    run += c[q];
  }
  __syncthreads();
  for (int i = s0 + t; i < e0; i += 256) {
    uint2 en = gbin[i];
    int lr = (int)(en.x >> 17);
    int pos = atomicAdd(&cnt[lr], 1);
    unsigned short h = f2h(__uint_as_float(en.y));
    ep[pos] = make_uint2((en.x & 0x1FFFFu) << 8, ((unsigned)h << 16) | (unsigned)h);
  }
  if (b == NBUCK - 1 && t == 0) offsets[N] = E;
}

// ---------------- fp32 -> fp16 converter (W only) ----------------
__global__ __launch_bounds__(256) void conv_f16(const float* __restrict__ in, unsigned short* __restrict__ outv, int n8) {
  int t = blockIdx.x * 256 + threadIdx.x;
  if (t >= n8) return;
  size_t base = (size_t)t * 8;
  float4 a = *(const float4*)&in[base];
  float4 b = *(const float4*)&in[base + 4];
  ushort4 o0, o1;
  o0.x = f2h(a.x); o0.y = f2h(a.y); o0.z = f2h(a.z); o0.w = f2h(a.w);
  o1.x = f2h(b.x); o1.y = f2h(b.y); o1.z = f2h(b.z); o1.w = f2h(b.w);
  *(ushort4*)&outv[base] = o0;
  *(ushort4*)&outv[base + 4] = o1;
}

// ---------------- GEMM (MFMA f16): Y[r][c] = sum_k X[r][k] * Wl[c][k] ----------------
// F32IN: X is fp32 (layer 0 reads emb directly), converted to f16 fragments inline.
template <int F32IN>
__global__ __launch_bounds__(256) void gemm_mfma(const void* __restrict__ xin,
                                                 const unsigned short* __restrict__ wb,
                                                 unsigned short* __restrict__ Y, int N) {
  int wave = threadIdx.x >> 6, lane = threadIdx.x & 63;
  int r0 = blockIdx.x * 64 + wave * 16;
  if (r0 >= N) return;
  int lr = lane & 15, lk = lane >> 4;
  f16x8 xf[4];
  if (F32IN) {
    const float* xrow = (const float*)xin + (size_t)(r0 + lr) * D + lk * 8;
#pragma unroll
    for (int s = 0; s < 4; ++s) {
      float4 a = *(const float4*)(xrow + 32 * s);
      float4 b = *(const float4*)(xrow + 32 * s + 4);
      f16x8 v;
      v[0] = (_Float16)a.x; v[1] = (_Float16)a.y; v[2] = (_Float16)a.z; v[3] = (_Float16)a.w;
      v[4] = (_Float16)b.x; v[5] = (_Float16)b.y; v[6] = (_Float16)b.z; v[7] = (_Float16)b.w;
      xf[s] = v;
    }
  } else {
    const unsigned short* xrow = (const unsigned short*)xin + (size_t)(r0 + lr) * D + lk * 8;
#pragma unroll
    for (int s = 0; s < 4; ++s) xf[s] = *(const f16x8*)(xrow + 32 * s);
  }
  f32x4 acc[8];
#pragma unroll
  for (int mt = 0; mt < 8; ++mt) acc[mt] = (f32x4){0.f, 0.f, 0.f, 0.f};
#pragma unroll
  for (int mt = 0; mt < 8; ++mt) {
    const unsigned short* wrow = wb + (size_t)(mt * 16 + lr) * D + lk * 8;
#pragma unroll
    for (int s = 0; s < 4; ++s) {
      f16x8 wf = *(const f16x8*)(wrow + 32 * s);
      acc[mt] = __builtin_amdgcn_mfma_f32_16x16x32_f16(wf, xf[s], acc[mt], 0, 0, 0);
    }
  }
#pragma unroll
  for (int mt = 0; mt < 8; ++mt) {
    ushort4 o;
    o.x = f2h(acc[mt][0]); o.y = f2h(acc[mt][1]); o.z = f2h(acc[mt][2]); o.w = f2h(acc[mt][3]);
    *(ushort4*)&Y[(size_t)(r0 + lr) * D + mt * 16 + lk * 4] = o;
  }
}

// ---------------- SpMM + ReLU -> fp16 Xn + row norm (packed half2, guarded gathers) ----------------
__global__ __launch_bounds__(256) void spmm_kernel(const char* __restrict__ Yb, const int* __restrict__ offs,
                                                   const uint2* __restrict__ ep,
                                                   unsigned* __restrict__ Xn, float* __restrict__ nrm, int N) {
  int w = threadIdx.x >> 6, lane = threadIdx.x & 63;
  int r = blockIdx.x * 4 + w;
  if (r >= N) return;
  int g = lane >> 4, l = lane & 15;
  int s = offs[r], e = offs[r + 1];
  unsigned acc[4] = {0u, 0u, 0u, 0u};   // 4x packed half2
  int loff = l * 16;
  for (int base = s; base < e; base += 32) {
    uint2 ed[8];
#pragma unroll
    for (int q = 0; q < 8; ++q) {
      int i = base + 4 * q + g;
      ed[q] = (i < e) ? ep[i] : make_uint2(0u, 0u);
    }
    uint4 yv[8];
#pragma unroll
    for (int q = 0; q < 8; ++q) yv[q] = *(const uint4*)(Yb + (size_t)(ed[q].x + loff));
#pragma unroll
    for (int q = 0; q < 8; ++q) {
      __half2 f2 = u2h(ed[q].y);
      unsigned uu[4] = {yv[q].x, yv[q].y, yv[q].z, yv[q].w};
#pragma unroll
      for (int k = 0; k < 4; ++k) {
        __half2 a2 = __hfma2(u2h(uu[k]), f2, u2h(acc[k]));
        acc[k] = h2u(a2);
      }
    }
  }
  // cross-group reduce (f16 packed), then ReLU
#pragma unroll
  for (int k = 0; k < 4; ++k) {
    unsigned a = acc[k];
    unsigned b = (unsigned)__shfl_xor((int)a, 16);
    a = h2u(__hadd2(u2h(a), u2h(b)));
    b = (unsigned)__shfl_xor((int)a, 32);
    a = relu2(h2u(__hadd2(u2h(a), u2h(b))));
    acc[k] = a;
  }
  // row norm (fp32 squares)
  float ss = 0.f;
#pragma unroll
  for (int k = 0; k < 4; ++k) {
    float lo = hlo(acc[k]), hi = hhi(acc[k]);
    ss = fmaf(lo, lo, ss);
    ss = fmaf(hi, hi, ss);
  }
  ss += __shfl_xor(ss, 1);
  ss += __shfl_xor(ss, 2);
  ss += __shfl_xor(ss, 4);
  ss += __shfl_xor(ss, 8);
  if (lane == 0) nrm[r] = sqrtf(ss);
  if (g == 0) {
    uint4 o = make_uint4(acc[0], acc[1], acc[2], acc[3]);
    *(uint4*)&Xn[(size_t)r * (D / 2) + l * 4] = o;
  }
}

// ---------------- final combine: 4 rows/wave; x0 term from fp32 emb ----------------
__global__ __launch_bounds__(256) void combine_kernel(const float* __restrict__ emb,
                                                      const unsigned short* __restrict__ x1,
                                                      const unsigned short* __restrict__ x2,
                                                      const unsigned short* __restrict__ x3,
                                                      const float* __restrict__ nrm,
                                                      float* __restrict__ out, int N, float scl) {
  int wave = threadIdx.x >> 6, lane = threadIdx.x & 63;
  int sub = lane >> 4, l = lane & 15;
  int r = blockIdx.x * 16 + wave * 4 + sub;
  if (r >= N) return;
  size_t p = (size_t)r * D + l * 8;
  float4 e0 = *(const float4*)&emb[p];
  float4 e1 = *(const float4*)&emb[p + 4];
  float v[8] = {e0.x, e0.y, e0.z, e0.w, e1.x, e1.y, e1.z, e1.w};
  float ss = 0.f;
#pragma unroll
  for (int k = 0; k < 8; ++k) ss = fmaf(v[k], v[k], ss);
  ss += __shfl_xor(ss, 1);
  ss += __shfl_xor(ss, 2);
  ss += __shfl_xor(ss, 4);
  ss += __shfl_xor(ss, 8);
  float s0 = scl / fmaxf(sqrtf(ss), 1e-12f);
  float i1 = scl / fmaxf(nrm[r], 1e-12f);
  float i2 = scl / fmaxf(nrm[N + r], 1e-12f);
  float i3 = scl / fmaxf(nrm[2 * N + r], 1e-12f);
  uint4 a1 = *(const uint4*)&x1[p];
  uint4 a2 = *(const uint4*)&x2[p];
  uint4 a3 = *(const uint4*)&x3[p];
  unsigned w1[4] = {a1.x, a1.y, a1.z, a1.w};
  unsigned w2[4] = {a2.x, a2.y, a2.z, a2.w};
  unsigned w3[4] = {a3.x, a3.y, a3.z, a3.w};
  float o[8];
#pragma unroll
  for (int k = 0; k < 4; ++k) {
    o[2 * k]     = s0 * v[2 * k]     + i1 * hlo(w1[k]) + i2 * hlo(w2[k]) + i3 * hlo(w3[k]);
    o[2 * k + 1] = s0 * v[2 * k + 1] + i1 * hhi(w1[k]) + i2 * hhi(w2[k]) + i3 * hhi(w3[k]);
  }
  *(float4*)&out[p]     = make_float4(o[0], o[1], o[2], o[3]);
  *(float4*)&out[p + 4] = make_float4(o[4], o[5], o[6], o[7]);
}

// ---------------- launch ----------------
extern "C" void kernel_launch(void* const* d_in, const int* in_sizes, int n_in,
                              void* d_out, int out_size, void* d_ws, size_t ws_size,
                              hipStream_t stream) {
  const int* rows = (const int*)d_in[0];
  const int* cols = (const int*)d_in[1];
  const float* vals = (const float*)d_in[2];
  const float* emb = (const float*)d_in[3];
  const float* W = (const float*)d_in[4];
  float* out = (float*)d_out;

  int E = in_sizes[0];
  int N = in_sizes[3] / D;
  int L = in_sizes[4] / (D * D);
  float scl = 1.0f / (float)(L + 1);

  int bshift = 10;
  int NBUCK = (N + (1 << bshift) - 1) >> bshift;

  int per = 4096;
  while ((E + per - 1) / per > 512) per *= 2;
  int NW = (E + per - 1) / per;

  char* ws = (char*)d_ws;
  size_t off = 0;
  auto take = [&](size_t bytes) -> void* {
    void* p = ws + off;
    off += (bytes + 255) & ~(size_t)255;
    return p;
  };
  unsigned short* xb1 = (unsigned short*)take((size_t)N * D * 2);
  unsigned short* xb2 = (unsigned short*)take((size_t)N * D * 2);
  unsigned short* xb3 = (unsigned short*)take((size_t)N * D * 2);
  unsigned short* yB  = (unsigned short*)take((size_t)N * D * 2);
  unsigned short* wb  = (unsigned short*)take((size_t)L * D * D * 2);
  float* nrm = (float*)take((size_t)L * N * sizeof(float));
  int* offsets = (int*)take((size_t)(N + 1) * 4);
  int* wghist = (int*)take((size_t)NBUCK_MAX * NW * 4);
  int* wgstart = (int*)take((size_t)NBUCK_MAX * NW * 4);
  int* btot = (int*)take((size_t)NBUCK_MAX * 4);
  int* bstart = (int*)take((size_t)(NBUCK_MAX + 1) * 4);
  uint2* ep = (uint2*)take((size_t)(E + 32) * 8);
  // gbin aliases xb1: consumed (debin2) strictly before spmm layer 0 writes xb1 (stream-ordered)
  uint2* gbin = (uint2*)xb1;

  // radix partition into buckets, then per-bucket offsets + scatter
  wg_hist<<<NW, 256, 0, stream>>>(rows, wghist, E, NW, per, bshift);
  scan_wg<<<NBUCK, 512, 0, stream>>>(wghist, wgstart, btot, NW);
  scan_buckets<<<1, 128, 0, stream>>>(btot, bstart, NBUCK);
  partition_kernel<<<NW, 256, 0, stream>>>(rows, cols, vals, wgstart, bstart, gbin, E, NW, per, bshift);
  debin2<<<NBUCK, 256, 0, stream>>>(gbin, bstart, offsets, ep, N, E, bshift, NBUCK);

  // fp16 conversion: W only
  int n8w = L * D * D / 8;
  conv_f16<<<(n8w + 255) / 256, 256, 0, stream>>>(W, wb, n8w);

  unsigned short* xbufs[4] = {nullptr, xb1, xb2, xb3};
  int nrb = (N + 63) / 64;
  for (int l = 0; l < L; ++l) {
    if (l == 0)
      gemm_mfma<1><<<nrb, 256, 0, stream>>>(emb, wb, yB, N);
    else
      gemm_mfma<0><<<nrb, 256, 0, stream>>>(xbufs[l], wb + (size_t)l * D * D, yB, N);
    spmm_kernel<<<(N + 3) / 4, 256, 0, stream>>>((const char*)yB, offsets, ep,
                                                 (unsigned*)xbufs[l + 1], nrm + (size_t)l * N, N);
  }
  combine_kernel<<<(N + 15) / 16, 256, 0, stream>>>(emb, xb1, xb2, xb3, nrm, out, N, scl);
}

// Round 12
// 368.079 us; speedup vs baseline: 1.1543x; 1.0121x over previous
//
#include <hip/hip_runtime.h>
#include <hip/hip_fp16.h>
#include <math.h>

#define D 128
#define NBUCK_MAX 128
#define BROWS 1024   // rows per bucket (bshift=10); requires N <= 131072 (col packs in 17 bits)

typedef _Float16 f16x8 __attribute__((ext_vector_type(8)));
typedef _Float16 f16x2 __attribute__((ext_vector_type(2)));
typedef __attribute__((ext_vector_type(4))) float f32x4;

static __device__ __forceinline__ unsigned short f2h(float f) {
  __half h = __float2half(f);
  return *reinterpret_cast<unsigned short*>(&h);
}
static __device__ __forceinline__ float hlo(unsigned u) {
  __half2 h = *reinterpret_cast<__half2*>(&u);
  return __low2float(h);
}
static __device__ __forceinline__ float hhi(unsigned u) {
  __half2 h = *reinterpret_cast<__half2*>(&u);
  return __high2float(h);
}
static __device__ __forceinline__ __half2 u2h(unsigned u) { return *reinterpret_cast<__half2*>(&u); }
static __device__ __forceinline__ unsigned h2u(__half2 h) { return *reinterpret_cast<unsigned*>(&h); }
static __device__ __forceinline__ unsigned relu2(unsigned u) {
  f16x2 v = *reinterpret_cast<f16x2*>(&u);
  v = __builtin_elementwise_max(v, (f16x2)(_Float16)0.0f);
  return *reinterpret_cast<unsigned*>(&v);
}

// ---- radix partition by bucket (row >> bshift), WG-private histograms ----
__global__ __launch_bounds__(256) void wg_hist(const int* __restrict__ rows, int* __restrict__ wghist,
                                               int E, int NW, int per, int bshift) {
  __shared__ int cnt[NBUCK_MAX];
  int tid = threadIdx.x, w = blockIdx.x;
  if (tid < NBUCK_MAX) cnt[tid] = 0;
  __syncthreads();
  int base = w * per;
  int end = base + per; if (end > E) end = E;
  for (int e = base + tid; e < end; e += 256) atomicAdd(&cnt[rows[e] >> bshift], 1);
  __syncthreads();
  if (tid < NBUCK_MAX) wghist[tid * NW + w] = cnt[tid];
}

__global__ __launch_bounds__(512) void scan_wg(const int* __restrict__ wghist, int* __restrict__ wgstart,
                                               int* __restrict__ btot, int NW) {
  int b = blockIdx.x, t = threadIdx.x;
  __shared__ int s[512];
  int v = (t < NW) ? wghist[b * NW + t] : 0;
  s[t] = v;
  __syncthreads();
  for (int d = 1; d < 512; d <<= 1) {
    int x = (t >= d) ? s[t - d] : 0;
    __syncthreads();
    s[t] += x;
    __syncthreads();
  }
  if (t < NW) wgstart[b * NW + t] = s[t] - v;
  if (t == 511) btot[b] = s[511];
}

// inclusive 128-wide prefix of btot into bp[] (LDS); call with >=128 threads, all hitting barriers
static __device__ __forceinline__ void scan_btot_lds(const int* __restrict__ btot, int* bp, int tid) {
  if (tid < NBUCK_MAX) bp[tid] = btot[tid];
  __syncthreads();
  for (int d = 1; d < NBUCK_MAX; d <<= 1) {
    int x = (tid >= d && tid < NBUCK_MAX) ? bp[tid - d] : 0;
    __syncthreads();
    if (tid < NBUCK_MAX) bp[tid] += x;
    __syncthreads();
  }
}

__global__ __launch_bounds__(256) void partition_kernel(const int* __restrict__ rows, const int* __restrict__ cols,
                                                        const float* __restrict__ vals, const int* __restrict__ wgstart,
                                                        const int* __restrict__ btot,
                                                        uint2* __restrict__ gbin, int E, int NW, int per, int bshift) {
  __shared__ int bp[NBUCK_MAX];
  __shared__ int cur[NBUCK_MAX];
  int tid = threadIdx.x, w = blockIdx.x;
  scan_btot_lds(btot, bp, tid);
  if (tid < NBUCK_MAX) cur[tid] = (tid ? bp[tid - 1] : 0) + wgstart[tid * NW + w];
  __syncthreads();
  unsigned rmask = (1u << bshift) - 1u;
  int base = w * per;
  int end = base + per; if (end > E) end = E;
  for (int e = base + tid; e < end; e += 256) {
    unsigned r = (unsigned)rows[e];
    int b = r >> bshift;
    int pos = atomicAdd(&cur[b], 1);
    gbin[pos] = make_uint2(((r & rmask) << 17) | (unsigned)cols[e], __float_as_uint(vals[e]));
  }
}

// per-bucket: LDS row-histogram + scan -> row offsets; scatter into final CSR ep
// ep entry: .x = Y-row byte offset (col*256), .y = val as packed half2 (h | h<<16)
__global__ __launch_bounds__(256) void debin2(const uint2* __restrict__ gbin, const int* __restrict__ btot,
                                              int* __restrict__ offsets, uint2* __restrict__ ep,
                                              int N, int E, int bshift, int NBUCK) {
  __shared__ int bp[NBUCK_MAX];
  __shared__ int cnt[BROWS];
  __shared__ int sblk[256];
  int b = blockIdx.x, t = threadIdx.x;
  scan_btot_lds(btot, bp, t);
  int s0 = (b ? bp[b - 1] : 0), e0 = bp[b];
  int r0 = b << bshift;
  int r1 = r0 + BROWS; if (r1 > N) r1 = N;
  int nr = r1 - r0;
#pragma unroll
  for (int q = 0; q < 4; ++q) cnt[t * 4 + q] = 0;
  __syncthreads();
  for (int i = s0 + t; i < e0; i += 256) atomicAdd(&cnt[gbin[i].x >> 17], 1);
  __syncthreads();
  int c[4]; int tsum = 0;
#pragma unroll
  for (int q = 0; q < 4; ++q) { c[q] = cnt[4 * t + q]; tsum += c[q]; }
  sblk[t] = tsum;
  __syncthreads();
  for (int d = 1; d < 256; d <<= 1) {
    int x = (t >= d) ? sblk[t - d] : 0;
    __syncthreads();
    sblk[t] += x;
    __syncthreads();
  }
  int run = s0 + sblk[t] - tsum;
#pragma unroll
  for (int q = 0; q < 4; ++q) {
    int j = 4 * t + q;
    if (j < nr) offsets[r0 + j] = run;
    cnt[j] = run;   // reuse as absolute cursor
    run += c[q];
  }
  __syncthreads();
  for (int i = s0 + t; i < e0; i += 256) {
    uint2 en = gbin[i];
    int lr = (int)(en.x >> 17);
    int pos = atomicAdd(&cnt[lr], 1);
    unsigned short h = f2h(__uint_as_float(en.y));
    ep[pos] = make_uint2((en.x & 0x1FFFFu) << 8, ((unsigned)h << 16) | (unsigned)h);
  }
  if (b == NBUCK - 1 && t == 0) offsets[N] = E;
}

// ---------------- fp32 -> fp16 converter (W only) ----------------
__global__ __launch_bounds__(256) void conv_f16(const float* __restrict__ in, unsigned short* __restrict__ outv, int n8) {
  int t = blockIdx.x * 256 + threadIdx.x;
  if (t >= n8) return;
  size_t base = (size_t)t * 8;
  float4 a = *(const float4*)&in[base];
  float4 b = *(const float4*)&in[base + 4];
  ushort4 o0, o1;
  o0.x = f2h(a.x); o0.y = f2h(a.y); o0.z = f2h(a.z); o0.w = f2h(a.w);
  o1.x = f2h(b.x); o1.y = f2h(b.y); o1.z = f2h(b.z); o1.w = f2h(b.w);
  *(ushort4*)&outv[base] = o0;
  *(ushort4*)&outv[base + 4] = o1;
}

// ---------------- GEMM (MFMA f16): Y[r][c] = sum_k X[r][k] * Wl[c][k] ----------------
template <int F32IN>
__global__ __launch_bounds__(256) void gemm_mfma(const void* __restrict__ xin,
                                                 const unsigned short* __restrict__ wb,
                                                 unsigned short* __restrict__ Y, int N) {
  int wave = threadIdx.x >> 6, lane = threadIdx.x & 63;
  int r0 = blockIdx.x * 64 + wave * 16;
  if (r0 >= N) return;
  int lr = lane & 15, lk = lane >> 4;
  f16x8 xf[4];
  if (F32IN) {
    const float* xrow = (const float*)xin + (size_t)(r0 + lr) * D + lk * 8;
#pragma unroll
    for (int s = 0; s < 4; ++s) {
      float4 a = *(const float4*)(xrow + 32 * s);
      float4 b = *(const float4*)(xrow + 32 * s + 4);
      f16x8 v;
      v[0] = (_Float16)a.x; v[1] = (_Float16)a.y; v[2] = (_Float16)a.z; v[3] = (_Float16)a.w;
      v[4] = (_Float16)b.x; v[5] = (_Float16)b.y; v[6] = (_Float16)b.z; v[7] = (_Float16)b.w;
      xf[s] = v;
    }
  } else {
    const unsigned short* xrow = (const unsigned short*)xin + (size_t)(r0 + lr) * D + lk * 8;
#pragma unroll
    for (int s = 0; s < 4; ++s) xf[s] = *(const f16x8*)(xrow + 32 * s);
  }
  f32x4 acc[8];
#pragma unroll
  for (int mt = 0; mt < 8; ++mt) acc[mt] = (f32x4){0.f, 0.f, 0.f, 0.f};
#pragma unroll
  for (int mt = 0; mt < 8; ++mt) {
    const unsigned short* wrow = wb + (size_t)(mt * 16 + lr) * D + lk * 8;
#pragma unroll
    for (int s = 0; s < 4; ++s) {
      f16x8 wf = *(const f16x8*)(wrow + 32 * s);
      acc[mt] = __builtin_amdgcn_mfma_f32_16x16x32_f16(wf, xf[s], acc[mt], 0, 0, 0);
    }
  }
#pragma unroll
  for (int mt = 0; mt < 8; ++mt) {
    ushort4 o;
    o.x = f2h(acc[mt][0]); o.y = f2h(acc[mt][1]); o.z = f2h(acc[mt][2]); o.w = f2h(acc[mt][3]);
    *(ushort4*)&Y[(size_t)(r0 + lr) * D + mt * 16 + lk * 4] = o;
  }
}

// ---------------- SpMM + ReLU (packed half2, guarded gathers) ----------------
// LAST=0: write fp16 Xn + row norm.  LAST=1: fuse final combine (read emb/x1/x2/nrm, write fp32 out).
template <int LAST>
__global__ __launch_bounds__(256) void spmm_kernel(const char* __restrict__ Yb, const int* __restrict__ offs,
                                                   const uint2* __restrict__ ep,
                                                   unsigned* __restrict__ Xn, float* __restrict__ nrm,
                                                   const float* __restrict__ emb,
                                                   const unsigned short* __restrict__ x1,
                                                   const unsigned short* __restrict__ x2,
                                                   float* __restrict__ outp, int N, float scl) {
  int w = threadIdx.x >> 6, lane = threadIdx.x & 63;
  int r = blockIdx.x * 4 + w;
  if (r >= N) return;
  int g = lane >> 4, l = lane & 15;
  int s = offs[r], e = offs[r + 1];
  unsigned acc[4] = {0u, 0u, 0u, 0u};   // 4x packed half2
  int loff = l * 16;
  for (int base = s; base < e; base += 32) {
    uint2 ed[8];
#pragma unroll
    for (int q = 0; q < 8; ++q) {
      int i = base + 4 * q + g;
      ed[q] = (i < e) ? ep[i] : make_uint2(0u, 0u);
    }
    uint4 yv[8];
#pragma unroll
    for (int q = 0; q < 8; ++q) yv[q] = *(const uint4*)(Yb + (size_t)(ed[q].x + loff));
#pragma unroll
    for (int q = 0; q < 8; ++q) {
      __half2 f2 = u2h(ed[q].y);
      unsigned uu[4] = {yv[q].x, yv[q].y, yv[q].z, yv[q].w};
#pragma unroll
      for (int k = 0; k < 4; ++k) {
        __half2 a2 = __hfma2(u2h(uu[k]), f2, u2h(acc[k]));
        acc[k] = h2u(a2);
      }
    }
  }
  // cross-group reduce (f16 packed), then ReLU
#pragma unroll
  for (int k = 0; k < 4; ++k) {
    unsigned a = acc[k];
    unsigned b = (unsigned)__shfl_xor((int)a, 16);
    a = h2u(__hadd2(u2h(a), u2h(b)));
    b = (unsigned)__shfl_xor((int)a, 32);
    a = relu2(h2u(__hadd2(u2h(a), u2h(b))));
    acc[k] = a;
  }
  // row norm of this layer's x (fp32 squares)
  float ss = 0.f;
#pragma unroll
  for (int k = 0; k < 4; ++k) {
    float lo = hlo(acc[k]), hi = hhi(acc[k]);
    ss = fmaf(lo, lo, ss);
    ss = fmaf(hi, hi, ss);
  }
  ss += __shfl_xor(ss, 1);
  ss += __shfl_xor(ss, 2);
  ss += __shfl_xor(ss, 4);
  ss += __shfl_xor(ss, 8);
  if (LAST == 0) {
    if (lane == 0) nrm[r] = sqrtf(ss);
    if (g == 0) {
      uint4 o = make_uint4(acc[0], acc[1], acc[2], acc[3]);
      *(uint4*)&Xn[(size_t)r * (D / 2) + l * 4] = o;
    }
  } else {
    if (g != 0) return;   // 16 lanes own the row (8 cols each)
    size_t p = (size_t)r * D + l * 8;
    float4 e0 = *(const float4*)&emb[p];
    float4 e1 = *(const float4*)&emb[p + 4];
    float v[8] = {e0.x, e0.y, e0.z, e0.w, e1.x, e1.y, e1.z, e1.w};
    float se = 0.f;
#pragma unroll
    for (int k = 0; k < 8; ++k) se = fmaf(v[k], v[k], se);
    se += __shfl_xor(se, 1);
    se += __shfl_xor(se, 2);
    se += __shfl_xor(se, 4);
    se += __shfl_xor(se, 8);
    float s0 = scl / fmaxf(sqrtf(se), 1e-12f);
    float i1 = scl / fmaxf(nrm[r], 1e-12f);
    float i2 = scl / fmaxf(nrm[N + r], 1e-12f);
    float i3 = scl / fmaxf(sqrtf(ss), 1e-12f);
    uint4 a1 = *(const uint4*)&x1[p];
    uint4 a2 = *(const uint4*)&x2[p];
    unsigned w1[4] = {a1.x, a1.y, a1.z, a1.w};
    unsigned w2[4] = {a2.x, a2.y, a2.z, a2.w};
    float o[8];
#pragma unroll
    for (int k = 0; k < 4; ++k) {
      o[2 * k]     = s0 * v[2 * k]     + i1 * hlo(w1[k]) + i2 * hlo(w2[k]) + i3 * hlo(acc[k]);
      o[2 * k + 1] = s0 * v[2 * k + 1] + i1 * hhi(w1[k]) + i2 * hhi(w2[k]) + i3 * hhi(acc[k]);
    }
    *(float4*)&outp[p]     = make_float4(o[0], o[1], o[2], o[3]);
    *(float4*)&outp[p + 4] = make_float4(o[4], o[5], o[6], o[7]);
  }
}

// ---------------- launch ----------------
extern "C" void kernel_launch(void* const* d_in, const int* in_sizes, int n_in,
                              void* d_out, int out_size, void* d_ws, size_t ws_size,
                              hipStream_t stream) {
  const int* rows = (const int*)d_in[0];
  const int* cols = (const int*)d_in[1];
  const float* vals = (const float*)d_in[2];
  const float* emb = (const float*)d_in[3];
  const float* W = (const float*)d_in[4];
  float* out = (float*)d_out;

  int E = in_sizes[0];
  int N = in_sizes[3] / D;
  int L = in_sizes[4] / (D * D);
  float scl = 1.0f / (float)(L + 1);

  int bshift = 10;
  int NBUCK = (N + (1 << bshift) - 1) >> bshift;

  int per = 4096;
  while ((E + per - 1) / per > 512) per *= 2;
  int NW = (E + per - 1) / per;

  char* ws = (char*)d_ws;
  size_t off = 0;
  auto take = [&](size_t bytes) -> void* {
    void* p = ws + off;
    off += (bytes + 255) & ~(size_t)255;
    return p;
  };
  unsigned short* xb1 = (unsigned short*)take((size_t)N * D * 2);
  unsigned short* xb2 = (unsigned short*)take((size_t)N * D * 2);
  unsigned short* yB  = (unsigned short*)take((size_t)N * D * 2);
  unsigned short* wb  = (unsigned short*)take((size_t)L * D * D * 2);
  float* nrm = (float*)take((size_t)L * N * sizeof(float));
  int* offsets = (int*)take((size_t)(N + 1) * 4);
  int* wghist = (int*)take((size_t)NBUCK_MAX * NW * 4);
  int* wgstart = (int*)take((size_t)NBUCK_MAX * NW * 4);
  int* btot = (int*)take((size_t)NBUCK_MAX * 4);
  uint2* ep = (uint2*)take((size_t)(E + 32) * 8);
  // gbin aliases xb1: consumed (debin2) strictly before spmm layer 0 writes xb1 (stream-ordered)
  uint2* gbin = (uint2*)xb1;

  // radix partition into buckets, then per-bucket offsets + scatter
  wg_hist<<<NW, 256, 0, stream>>>(rows, wghist, E, NW, per, bshift);
  scan_wg<<<NBUCK, 512, 0, stream>>>(wghist, wgstart, btot, NW);
  partition_kernel<<<NW, 256, 0, stream>>>(rows, cols, vals, wgstart, btot, gbin, E, NW, per, bshift);
  debin2<<<NBUCK, 256, 0, stream>>>(gbin, btot, offsets, ep, N, E, bshift, NBUCK);

  // fp16 conversion: W only
  int n8w = L * D * D / 8;
  conv_f16<<<(n8w + 255) / 256, 256, 0, stream>>>(W, wb, n8w);

  int nrb = (N + 63) / 64;
  int nsb = (N + 3) / 4;
  // layer 0
  gemm_mfma<1><<<nrb, 256, 0, stream>>>(emb, wb, yB, N);
  spmm_kernel<0><<<nsb, 256, 0, stream>>>((const char*)yB, offsets, ep, (unsigned*)xb1, nrm, nullptr, nullptr, nullptr, nullptr, N, scl);
  // layer 1
  gemm_mfma<0><<<nrb, 256, 0, stream>>>(xb1, wb + (size_t)D * D, yB, N);
  spmm_kernel<0><<<nsb, 256, 0, stream>>>((const char*)yB, offsets, ep, (unsigned*)xb2, nrm + N, nullptr, nullptr, nullptr, nullptr, N, scl);
  // layer 2 fused with final combine
  gemm_mfma<0><<<nrb, 256, 0, stream>>>(xb2, wb + (size_t)2 * D * D, yB, N);
  spmm_kernel<1><<<nsb, 256, 0, stream>>>((const char*)yB, offsets, ep, nullptr, nrm, emb, xb1, xb2, out, N, scl);
}